// Round 16
// baseline (704.694 us; speedup 1.0000x reference)
//
#include <hip/hip_runtime.h>
#include <math.h>

#define DDIM 100   // embed dim
#define PFD  4     // k_bigmm LDS ring depth
#define NTG  4     // k_bigmm n-tiles per store group

using short8 = __attribute__((ext_vector_type(8))) short;
using f32x4  = __attribute__((ext_vector_type(4))) float;

// ---------------------------------------------------------------- utilities

__device__ __forceinline__ float sigm(float x) { return 1.f / (1.f + expf(-x)); }

__device__ __forceinline__ f32x4 mfma16(short8 a, short8 b, f32x4 c) {
  return __builtin_amdgcn_mfma_f32_16x16x32_bf16(a, b, c, 0, 0, 0);
}

__device__ __forceinline__ void gld_lds16(const void* g, void* l) {
  __builtin_amdgcn_global_load_lds(
      (const __attribute__((address_space(1))) void*)g,
      (__attribute__((address_space(3))) void*)l, 16, 0, 0);
}

// RNE bf16 split: v ~= hi + lo
__device__ __forceinline__ void bf16split(float v, short& h, short& l) {
  unsigned u = __float_as_uint(v);
  unsigned hb = (u + 0x7fffu + ((u >> 16) & 1u)) & 0xffff0000u;
  float res = v - __uint_as_float(hb);
  unsigned u2 = __float_as_uint(res);
  h = (short)(hb >> 16);
  l = (short)((u2 + 0x7fffu + ((u2 >> 16) & 1u)) >> 16);
}

__device__ __forceinline__ short bf16hi(float v) {
  unsigned u = __float_as_uint(v);
  return (short)((u + 0x7fffu + ((u >> 16) & 1u)) >> 16);
}

// ---------------------------------------------------------------- combined pack + gather
__global__ void k_packAll(const int* __restrict__ x, const float* __restrict__ emb,
                          const int* __restrict__ batch,
                          const float* __restrict__ w_ih, const float* __restrict__ conv_w,
                          const float* __restrict__ w_hh, const float* __restrict__ w2,
                          const float* __restrict__ w3,
                          short8* __restrict__ Bhi, short8* __restrict__ Blo,
                          short8* __restrict__ Whi,
                          float4* __restrict__ h0, int* __restrict__ last_idx,
                          int NNODE, int NT, int N) {
  int gid = blockIdx.x * 256 + threadIdx.x;
  const int embN = NT * 4 * 64;
  const int wN = 8 * 7 * 4 * 64;
  if (gid < embN) {
    int lane = gid & 63;
    int kt = (gid >> 6) & 3;
    int rt = gid >> 8;
    int r = rt * 16 + (lane & 15);
    if (r >= NNODE) r = NNODE - 1;
    int k0 = kt * 32 + (lane >> 4) * 8;
    float4 f0 = make_float4(0.f, 0.f, 0.f, 0.f);
    float4 f1 = make_float4(0.f, 0.f, 0.f, 0.f);
    if (k0 < 100)     f0 = *(const float4*)(emb + (size_t)r * DDIM + k0);
    if (k0 + 4 < 100) f1 = *(const float4*)(emb + (size_t)r * DDIM + k0 + 4);
    float v[8] = {f0.x, f0.y, f0.z, f0.w, f1.x, f1.y, f1.z, f1.w};
    short8 h, l;
#pragma unroll
    for (int j = 0; j < 8; ++j) {
      short hh, ll;
      bf16split(v[j], hh, ll);
      h[j] = hh; l[j] = ll;
    }
    Bhi[gid] = h;
    Blo[gid] = l;
  } else if (gid < embN + wN) {
    int wg = gid - embN;
    int lane = wg & 63;
    int kt = (wg >> 6) & 3;
    int snt = wg >> 8;
    int nt = snt % 7;
    int s = snt / 7;
    int d = nt * 16 + (lane & 15);
    int k0 = kt * 32 + (lane >> 4) * 8;
    short8 h;
#pragma unroll
    for (int j = 0; j < 8; ++j) {
      int k = k0 + j;
      float v = 0.f;
      if (d < 100 && k < 100) {
        if (s < 3) {
          const float* wr = w_ih + (size_t)(s * 100 + d) * 100;
          const float* cr = conv_w + (size_t)k * 100;
          float acc = 0.f;
          for (int t = 0; t < 100; ++t) acc = fmaf(wr[t], cr[t], acc);
          v = acc;
        } else if (s < 6) {
          v = w_hh[(size_t)((s - 3) * 100 + d) * 100 + k];
        } else if (s == 6) {
          v = w2[(size_t)d * 100 + k];
        } else {
          v = w3[(size_t)d * 100 + k];
        }
      }
      h[j] = bf16hi(v);
    }
    Whi[wg] = h;
  } else {
    int i = gid - embN - wN;
    if (i < N * 25) {
      int node = i / 25, c = i - node * 25;
      h0[i] = *(const float4*)(emb + (size_t)(x[node] - 1) * DDIM + 4 * c);
    }
    if (i < N) {
      if (i == N - 1 || batch[i + 1] != batch[i]) last_idx[batch[i]] = i;
    }
  }
}

// ---------------------------------------------------------------- aggregation
__global__ __launch_bounds__(512, 1) void k_aggregate(
    const int* __restrict__ ei, const float* __restrict__ h0,
    float* __restrict__ aggH, int E) {
  __shared__ float acc[256 * DDIM];  // 100 KB
  const int tid = threadIdx.x;
  const int lane = tid & 63;
  const int wave = tid >> 6;         // 0..7
  const int r0 = blockIdx.x * 256;

  for (int idx = tid; idx < 256 * DDIM / 4; idx += 512)
    ((float4*)acc)[idx] = make_float4(0.f, 0.f, 0.f, 0.f);
  __syncthreads();

  const int per = E >> 3;            // multiple of 256
  const int base = wave * per;
  for (int it = 0; it < per; it += 256) {
    int e0 = base + it + lane * 4;
    int4 d4 = *(const int4*)(ei + E + e0);
    int4 s4 = *(const int4*)(ei + e0);
    int darr[4] = {d4.x, d4.y, d4.z, d4.w};
    int sarr[4] = {s4.x, s4.y, s4.z, s4.w};
#pragma unroll
    for (int j = 0; j < 4; ++j) {
      int dj = darr[j] - r0;
      bool match = (unsigned)dj < 256u;
      unsigned long long mask = __ballot(match);
      while (mask) {
        int bit = __ffsll(mask) - 1;
        mask &= mask - 1;
        int ds = __shfl(dj, bit, 64);
        int ss = __shfl(sarr[j], bit, 64);
        if (lane < 25) {
          float4 v = *(const float4*)(h0 + (size_t)ss * DDIM + 4 * lane);
          float* a = acc + ds * DDIM + 4 * lane;
          atomicAdd(a + 0, v.x); atomicAdd(a + 1, v.y);
          atomicAdd(a + 2, v.z); atomicAdd(a + 3, v.w);
        }
      }
    }
  }
  __syncthreads();
  float4* of = (float4*)(aggH + (size_t)r0 * DDIM);
  for (int idx = tid; idx < 256 * DDIM / 4; idx += 512)
    of[idx] = ((const float4*)acc)[idx];
}

// ---------------------------------------------------------------- session pooling
__global__ __launch_bounds__(256) void k_session(
    const float* __restrict__ xh, const float* __restrict__ t2,
    const float* __restrict__ t3v,
    const float* __restrict__ q_w, const float* __restrict__ q_b,
    const int* __restrict__ last_idx, float* __restrict__ Scat, int B) {
  int sid = blockIdx.x * 4 + (threadIdx.x >> 6);
  if (sid >= B) return;
  const int lane = threadIdx.x & 63;
  const int g = lane >> 4;
  const int s = lane & 15;
  const int start = (sid == 0) ? 0 : last_idx[sid - 1] + 1;
  const int end = last_idx[sid];

  float vr[7], t3r[7], qr[7];
#pragma unroll
  for (int k = 0; k < 7; ++k) {
    int c = s + 16 * k;
    bool ok = c < DDIM;
    vr[k]  = ok ? xh[(size_t)end * DDIM + c] : 0.f;
    t3r[k] = ok ? t3v[(size_t)sid * DDIM + c] : 0.f;
    qr[k]  = ok ? q_w[c] : 0.f;
  }
  const float qb = q_b[0];

  float m = -INFINITY, den = 0.f;
  float ss[7] = {}, sg[7] = {};
  for (int i = start; i <= end; i += 4) {
    int ni = i + g;
    bool act = ni <= end;
    int nrow = act ? ni : end;
    float xv[7];
    float l = 0.f, ga = 0.f;
#pragma unroll
    for (int k = 0; k < 7; ++k) {
      int c = s + 16 * k;
      float x = (c < DDIM) ? xh[(size_t)nrow * DDIM + c] : 0.f;
      float tv = (c < DDIM) ? t2[(size_t)nrow * DDIM + c] : 0.f;
      xv[k] = x;
      l = fmaf(x, vr[k], l);
      ga = fmaf(qr[k], sigm(tv + t3r[k]), ga);
    }
#pragma unroll
    for (int o = 1; o <= 8; o <<= 1) {
      l += __shfl_xor(l, o, 64);
      ga += __shfl_xor(ga, o, 64);
    }
    float ls = act ? l : -INFINITY;
    float alpha = act ? (ga + qb) : 0.f;
    float mn = fmaxf(m, ls);
    float cf = (m == -INFINITY) ? 0.f : expf(m - mn);
    float p = act ? expf(ls - mn) : 0.f;
    den = den * cf + p;
#pragma unroll
    for (int k = 0; k < 7; ++k) {
      ss[k] = ss[k] * cf + p * xv[k];
      sg[k] = fmaf(alpha, xv[k], sg[k]);
    }
    m = mn;
  }
  float mAll = m;
  mAll = fmaxf(mAll, __shfl_xor(mAll, 16, 64));
  mAll = fmaxf(mAll, __shfl_xor(mAll, 32, 64));
  float sc = (m == -INFINITY) ? 0.f : expf(m - mAll);
  float dv = den * sc;
  dv += __shfl_xor(dv, 16, 64);
  dv += __shfl_xor(dv, 32, 64);
  float inv = 1.f / dv;
  float* Sc = Scat + (size_t)sid * 300;
#pragma unroll
  for (int k = 0; k < 7; ++k) {
    float sv = ss[k] * sc;
    float gv = sg[k];
    sv += __shfl_xor(sv, 16, 64);  sv += __shfl_xor(sv, 32, 64);
    gv += __shfl_xor(gv, 16, 64);  gv += __shfl_xor(gv, 32, 64);
    int c = s + 16 * k;
    if (g == 0 && c < DDIM) {
      Sc[c] = sv * inv;
      Sc[100 + c] = gv;
      Sc[200 + c] = vr[k];
    }
  }
}

// hi-only A fragment loads for one 16-row m-tile (K=100 padded to 128)
__device__ __forceinline__ void load_afragsH(const float* __restrict__ A, int rowBase,
                                             int lane, short8 ah[4]) {
  int r = rowBase + (lane & 15);
  int g = lane >> 4;
#pragma unroll
  for (int kt = 0; kt < 4; ++kt) {
    int k0 = kt * 32 + g * 8;
    float4 f0 = make_float4(0.f, 0.f, 0.f, 0.f);
    float4 f1 = make_float4(0.f, 0.f, 0.f, 0.f);
    if (k0 < 100)     f0 = *(const float4*)(A + (size_t)r * DDIM + k0);
    if (k0 + 4 < 100) f1 = *(const float4*)(A + (size_t)r * DDIM + k0 + 4);
    short8 h;
    h[0] = bf16hi(f0.x); h[1] = bf16hi(f0.y); h[2] = bf16hi(f0.z); h[3] = bf16hi(f0.w);
    h[4] = bf16hi(f1.x); h[5] = bf16hi(f1.y); h[6] = bf16hi(f1.z); h[7] = bf16hi(f1.w);
    ah[kt] = h;
  }
}

__device__ __forceinline__ void load_afragsHg(const float* __restrict__ A,
                                              const int* __restrict__ idx, int base,
                                              int lane, short8 ah[4]) {
  int r = idx[base + (lane & 15)];
  int g = lane >> 4;
#pragma unroll
  for (int kt = 0; kt < 4; ++kt) {
    int k0 = kt * 32 + g * 8;
    float4 f0 = make_float4(0.f, 0.f, 0.f, 0.f);
    float4 f1 = make_float4(0.f, 0.f, 0.f, 0.f);
    if (k0 < 100)     f0 = *(const float4*)(A + (size_t)r * DDIM + k0);
    if (k0 + 4 < 100) f1 = *(const float4*)(A + (size_t)r * DDIM + k0 + 4);
    short8 h;
    h[0] = bf16hi(f0.x); h[1] = bf16hi(f0.y); h[2] = bf16hi(f0.z); h[3] = bf16hi(f0.w);
    h[4] = bf16hi(f1.x); h[5] = bf16hi(f1.y); h[6] = bf16hi(f1.z); h[7] = bf16hi(f1.w);
    ah[kt] = h;
  }
}

// ---------------------------------------------------------------- fused GGC+GRU
__global__ __launch_bounds__(256) void k_grufused(
    const float* __restrict__ aggH, const float* __restrict__ h0,
    const short8* __restrict__ Whi,
    const float* __restrict__ b_ih, const float* __restrict__ b_hh,
    float* __restrict__ xh) {
  const int lane = threadIdx.x & 63;
  const int wave = threadIdx.x >> 6;
  const int rowBase = blockIdx.x * 128 + wave * 32;
  short8 aI0[4], aI1[4], aH0[4], aH1[4];
  load_afragsH(aggH, rowBase, lane, aI0);
  load_afragsH(aggH, rowBase + 16, lane, aI1);
  load_afragsH(h0, rowBase, lane, aH0);
  load_afragsH(h0, rowBase + 16, lane, aH1);
  const int c0 = lane & 15;
  const int r0 = (lane >> 4) * 4;

  for (int nt = 0; nt < 7; ++nt) {
    int d = nt * 16 + c0;
    f32x4 a0[6] = {};
    f32x4 a1[6] = {};
#pragma unroll
    for (int s = 0; s < 6; ++s) {
#pragma unroll
      for (int kt = 0; kt < 4; ++kt) {
        short8 w = Whi[(((size_t)s * 7 + nt) * 4 + kt) * 64 + lane];
        if (s < 3) {
          a0[s] = mfma16(aI0[kt], w, a0[s]);
          a1[s] = mfma16(aI1[kt], w, a1[s]);
        } else {
          a0[s] = mfma16(aH0[kt], w, a0[s]);
          a1[s] = mfma16(aH1[kt], w, a1[s]);
        }
      }
    }
    if (d < 100) {
      float bir = b_ih[d], biz = b_ih[100 + d], bin_ = b_ih[200 + d];
      float bhr = b_hh[d], bhz = b_hh[100 + d], bhn = b_hh[200 + d];
#pragma unroll
      for (int ri = 0; ri < 4; ++ri) {
        {
          int row = rowBase + r0 + ri;
          float r = sigm(a0[0][ri] + bir + a0[3][ri] + bhr);
          float z = sigm(a0[1][ri] + biz + a0[4][ri] + bhz);
          float n = tanhf(a0[2][ri] + bin_ + r * (a0[5][ri] + bhn));
          float h0v = h0[(size_t)row * DDIM + d];
          float v = (1.f - z) * n + z * h0v;
          xh[(size_t)row * DDIM + d] = v > 0.f ? v : 0.f;
        }
        {
          int row = rowBase + 16 + r0 + ri;
          float r = sigm(a1[0][ri] + bir + a1[3][ri] + bhr);
          float z = sigm(a1[1][ri] + biz + a1[4][ri] + bhz);
          float n = tanhf(a1[2][ri] + bin_ + r * (a1[5][ri] + bhn));
          float h0v = h0[(size_t)row * DDIM + d];
          float v = (1.f - z) * n + z * h0v;
          xh[(size_t)row * DDIM + d] = v > 0.f ? v : 0.f;
        }
      }
    }
  }
}

// t2 = xh @ w2^T + b2 (blocks < nblkA) ; t3v = xh[lastI] @ w3^T + b3 (rest)
__global__ __launch_bounds__(256) void k_mm100t3(
    const float* __restrict__ xh, const short8* __restrict__ Whi,
    const float* __restrict__ b2, const float* __restrict__ b3,
    const int* __restrict__ lastI,
    float* __restrict__ t2, float* __restrict__ t3v, int nblkA) {
  const int bb = blockIdx.x;
  const int lane = threadIdx.x & 63;
  const int wave = threadIdx.x >> 6;
  const bool isT3 = bb >= nblkA;
  const int setIdx = isT3 ? 7 : 6;
  const float* bias = isT3 ? b3 : b2;
  float* out = isT3 ? t3v : t2;
  const int rowBase = (isT3 ? (bb - nblkA) : bb) * 128 + wave * 32;

  short8 a0[4], a1[4];
  if (isT3) {
    load_afragsHg(xh, lastI, rowBase, lane, a0);
    load_afragsHg(xh, lastI, rowBase + 16, lane, a1);
  } else {
    load_afragsH(xh, rowBase, lane, a0);
    load_afragsH(xh, rowBase + 16, lane, a1);
  }
  const int c0 = lane & 15;
  const int r0 = (lane >> 4) * 4;

  for (int nt = 0; nt < 7; ++nt) {
    int d = nt * 16 + c0;
    f32x4 ac0 = {0.f, 0.f, 0.f, 0.f};
    f32x4 ac1 = {0.f, 0.f, 0.f, 0.f};
#pragma unroll
    for (int kt = 0; kt < 4; ++kt) {
      short8 w = Whi[(((size_t)setIdx * 7 + nt) * 4 + kt) * 64 + lane];
      ac0 = mfma16(a0[kt], w, ac0);
      ac1 = mfma16(a1[kt], w, ac1);
    }
    if (d < 100) {
      float b = bias[d];
#pragma unroll
      for (int ri = 0; ri < 4; ++ri) {
        out[(size_t)(rowBase + r0 + ri) * DDIM + d] = ac0[ri] + b;
        out[(size_t)(rowBase + 16 + r0 + ri) * DDIM + d] = ac1[ri] + b;
      }
    }
  }
}

// ---------------------------------------------------------------- S GEMM -> packed frags
__global__ __launch_bounds__(256, 2) void k_gemmS(
    const float* __restrict__ A, const float* __restrict__ Bm,
    const float* __restrict__ bias, short* __restrict__ Ph, short* __restrict__ Pl,
    int M) {
  __shared__ float4 As4[25 * 128];
  __shared__ float4 Bs4[25 * 64];
  const int m0 = blockIdx.y * 128;
  const int n0 = blockIdx.x * 64;
  const int t = threadIdx.x;
  const int tx = t & 15;
  const int ty = t >> 4;
  float acc[8][4] = {};

  for (int kt = 0; kt < 300; kt += 100) {
    for (int idx = t; idx < 128 * 25; idx += 256) {
      int r = idx / 25, k4 = idx - r * 25;
      int ar = m0 + r; if (ar >= M) ar = M - 1;
      float4 v = *(const float4*)(A + (size_t)ar * 300 + kt + 4 * k4);
      As4[k4 * 128 + (r ^ (k4 & 7))] = v;
    }
    for (int idx = t; idx < 64 * 25; idx += 256) {
      int r = idx / 25, k4 = idx - r * 25;
      int br = n0 + r;
      float4 v = make_float4(0.f, 0.f, 0.f, 0.f);
      if (br < 100) v = *(const float4*)(Bm + (size_t)br * 300 + kt + 4 * k4);
      Bs4[k4 * 64 + (r ^ (k4 & 7))] = v;
    }
    __syncthreads();
#pragma unroll 5
    for (int k4 = 0; k4 < 25; ++k4) {
      const int s = k4 & 7;
      float4 av[8], bv[4];
#pragma unroll
      for (int i = 0; i < 8; ++i) av[i] = As4[k4 * 128 + ((ty + 16 * i) ^ s)];
#pragma unroll
      for (int j = 0; j < 4; ++j) bv[j] = Bs4[k4 * 64 + ((tx + 16 * j) ^ s)];
#pragma unroll
      for (int i = 0; i < 8; ++i) {
#pragma unroll
        for (int j = 0; j < 4; ++j) {
          acc[i][j] = fmaf(av[i].x, bv[j].x, acc[i][j]);
          acc[i][j] = fmaf(av[i].y, bv[j].y, acc[i][j]);
          acc[i][j] = fmaf(av[i].z, bv[j].z, acc[i][j]);
          acc[i][j] = fmaf(av[i].w, bv[j].w, acc[i][j]);
        }
      }
    }
    __syncthreads();
  }

#pragma unroll
  for (int i = 0; i < 8; ++i) {
    int row = m0 + ty + 16 * i;
    if (row >= M) continue;
#pragma unroll
    for (int j = 0; j < 4; ++j) {
      int col = n0 + tx + 16 * j;   // 0..127 (>=100 -> zero pad slot)
      float v = (col < 100) ? (acc[i][j] + bias[col]) : 0.f;
      short hh, ll;
      bf16split(v, hh, ll);
      int rt = row >> 4, kt = col >> 5;
      int lane_t = (row & 15) + 16 * ((col >> 3) & 3);
      size_t base = ((((size_t)rt * 4 + kt) * 64 + lane_t) << 3) + (col & 7);
      Ph[base] = hh;
      Pl[base] = ll;
    }
  }
}

// ---------------------------------------------------------------- big MFMA GEMM (r7-verbatim)
__global__ __launch_bounds__(256) void k_bigmm(
    const short8* __restrict__ Ahi, const short8* __restrict__ Alo,
    const short8* __restrict__ Bhi, const short8* __restrict__ Blo,
    float* __restrict__ out, int NT, int NTCHUNK, int NCOLS) {
  __shared__ short8 Bs[PFD * 8 * 64];   // 32 KB ring
  __shared__ float Xp[4 * 32 * 64];     // 32 KB transpose stripes (8KB/wave)
  const int lane = threadIdx.x & 63;
  const int wave = threadIdx.x >> 6;
  const int mt0 = blockIdx.x * 8 + wave * 2;

  short8 ah[2][4], al[2][4];
#pragma unroll
  for (int mi = 0; mi < 2; ++mi)
#pragma unroll
    for (int kt = 0; kt < 4; ++kt) {
      size_t off = ((size_t)(mt0 + mi) * 4 + kt) * 64 + lane;
      ah[mi][kt] = Ahi[off];
      al[mi][kt] = Alo[off];
    }

  const int nt0 = blockIdx.y * NTCHUNK;
  const int nt1 = min(NT, nt0 + NTCHUNK);
  const int r0 = (lane >> 4) * 4;
  const int c0 = lane & 15;
  float* xp = &Xp[wave * 32 * 64];

  auto issueB = [&](int nt) {
    int s = nt & (PFD - 1);
    gld_lds16(Bhi + ((size_t)nt * 4 + wave) * 64 + lane, &Bs[(s * 8 + wave) * 64]);
    gld_lds16(Blo + ((size_t)nt * 4 + wave) * 64 + lane, &Bs[(s * 8 + 4 + wave) * 64]);
  };

  for (int i = 0; i < PFD && nt0 + i < nt1; ++i) issueB(nt0 + i);
  asm volatile("s_waitcnt vmcnt(6)" ::: "memory");
  __builtin_amdgcn_s_barrier();

  for (int g = nt0; g < nt1; g += NTG) {
    const int jn = min(NTG, nt1 - g);
    f32x4 acc[2][NTG] = {};
#pragma unroll
    for (int j = 0; j < NTG; ++j) {
      if (j >= jn) break;
      const int nt = g + j;
      const int s = nt & (PFD - 1);
      short8 bh[4], bl[4];
#pragma unroll
      for (int kt = 0; kt < 4; ++kt) {
        bh[kt] = Bs[(s * 8 + kt) * 64 + lane];
        bl[kt] = Bs[(s * 8 + 4 + kt) * 64 + lane];
      }
      asm volatile("s_waitcnt lgkmcnt(0)" ::: "memory");
      __builtin_amdgcn_s_barrier();
      if (nt + PFD < nt1) issueB(nt + PFD);
      __builtin_amdgcn_sched_barrier(0);
#pragma unroll
      for (int kt = 0; kt < 4; ++kt) {
        acc[0][j] = mfma16(ah[0][kt], bh[kt], acc[0][j]);
        acc[1][j] = mfma16(ah[1][kt], bh[kt], acc[1][j]);
        acc[0][j] = mfma16(ah[0][kt], bl[kt], acc[0][j]);
        acc[1][j] = mfma16(ah[1][kt], bl[kt], acc[1][j]);
        acc[0][j] = mfma16(al[0][kt], bh[kt], acc[0][j]);
        acc[1][j] = mfma16(al[1][kt], bh[kt], acc[1][j]);
      }
      asm volatile("s_waitcnt vmcnt(14)" ::: "memory");
      __builtin_amdgcn_s_barrier();
    }
#pragma unroll
    for (int mi = 0; mi < 2; ++mi)
#pragma unroll
      for (int j = 0; j < NTG; ++j) {
        if (j < jn) {
#pragma unroll
          for (int r = 0; r < 4; ++r) {
            int rl = mi * 16 + r0 + r;
            int cl = j * 16 + c0;
            xp[rl * 64 + (cl ^ (((rl >> 2) & 3) << 4))] = acc[mi][j][r];
          }
        }
      }
    const int colbase = g * 16;
#pragma unroll
    for (int it = 0; it < 8; ++it) {
      int rl = it * 4 + (lane >> 4);
      int cl = 4 * c0;
      if (cl < jn * 16) {
        f32x4 v = *(const f32x4*)&xp[rl * 64 + (cl ^ (((rl >> 2) & 3) << 4))];
        int row = mt0 * 16 + rl;
        __builtin_nontemporal_store(v, (f32x4*)(out + (size_t)row * NCOLS + colbase + cl));
      }
    }
  }
}

// ---------------------------------------------------------------- launcher

extern "C" void kernel_launch(void* const* d_in, const int* in_sizes, int n_in,
                              void* d_out, int out_size, void* d_ws, size_t ws_size,
                              hipStream_t stream) {
  const int*   x      = (const int*)d_in[0];
  const int*   ei     = (const int*)d_in[1];
  const int*   batch  = (const int*)d_in[2];
  const float* emb    = (const float*)d_in[4];
  const float* conv_w = (const float*)d_in[5];
  const float* w_ih   = (const float*)d_in[6];
  const float* w_hh   = (const float*)d_in[7];
  const float* b_ih   = (const float*)d_in[8];
  const float* b_hh   = (const float*)d_in[9];
  const float* q_w    = (const float*)d_in[10];
  const float* q_b    = (const float*)d_in[11];
  const float* w2     = (const float*)d_in[12];
  const float* b2     = (const float*)d_in[13];
  const float* w3     = (const float*)d_in[14];
  const float* b3     = (const float*)d_in[15];
  const float* w4     = (const float*)d_in[16];
  const float* b4     = (const float*)d_in[17];

  const int N = in_sizes[0];            // 49152
  const int E = in_sizes[1] / 2;        // 98304
  const int NNODE = in_sizes[4] / DDIM; // 50000
  const int B = out_size / NNODE;       // 4096

  size_t ND = (size_t)N * DDIM;
  float* ws   = (float*)d_ws;
  float* h0   = ws;            // [N,100]
  float* aggH = ws + ND;       // [N,100]
  float* xh   = ws + 2 * ND;   // [N,100]
  float* t2   = ws + 3 * ND;   // [N,100]
  float* aux  = ws + 4 * ND;
  float* t3v  = aux;                           // [B,100]
  float* Scat = t3v + (size_t)B * DDIM;        // [B,300]
  int*   lastI = (int*)(Scat + 3 * (size_t)B * DDIM); // [B]

  const int MT = (B + 15) / 16;          // 256
  const int NT = (NNODE + 15) / 16;      // 3125
  short8* Whi = (short8*)(lastI + B);    // 8 sets x [7][4][64]
  short8* Ahi = Whi + 8 * 7 * 4 * 64;
  short8* Alo = Ahi + (size_t)MT * 4 * 64;
  short8* Bhi = Alo + (size_t)MT * 4 * 64;
  short8* Blo = Bhi + (size_t)NT * 4 * 64;

  dim3 blk(256);
  const int nblkA = N / 128;   // 384
  const int nblkB = B / 128;   // 32

  int packTotal = NT * 4 * 64 + 8 * 7 * 4 * 64 + N * 25;
  // MEASUREMENT: run the entire (idempotent) chain TWICE.
  // dur - r13's 453 = one warm chain pass (F and bigmm cancel).
  for (int rep = 0; rep < 2; ++rep) {
    k_packAll<<<(packTotal + 255) / 256, blk, 0, stream>>>(
        x, emb, batch, w_ih, conv_w, w_hh, w2, w3, Bhi, Blo, Whi,
        (float4*)h0, lastI, NNODE, NT, N);
    k_aggregate<<<N / 256, dim3(512), 0, stream>>>(ei, h0, aggH, E);
    k_grufused<<<nblkA, blk, 0, stream>>>(aggH, h0, Whi, b_ih, b_hh, xh);
    k_mm100t3<<<nblkA + nblkB, blk, 0, stream>>>(xh, Whi, b2, b3, lastI, t2, t3v, nblkA);
    k_session<<<(B + 3) / 4, blk, 0, stream>>>(xh, t2, t3v, q_w, q_b, lastI, Scat, B);
    k_gemmS<<<dim3(2, B / 128), blk, 0, stream>>>(Scat, w4, b4, (short*)Ahi, (short*)Alo, B);
  }

  const int NTCHUNK = 48;                            // multiple of NTG
  const int NCHUNKS = (NT + NTCHUNK - 1) / NTCHUNK;  // 66
  k_bigmm<<<dim3(nblkB, NCHUNKS), blk, 0, stream>>>(
      Ahi, Alo, Bhi, Blo, (float*)d_out, NT, NTCHUNK, NNODE);
}

// Round 17
// 404.293 us; speedup vs baseline: 1.7430x; 1.7430x over previous
//
#include <hip/hip_runtime.h>
#include <math.h>

#define DDIM 100   // embed dim
#define PFD  4     // k_bigmm LDS ring depth
#define NTG  4     // k_bigmm n-tiles per store group
#define XS   108   // grufused LDS stripe stride (16B-aligned, 2-way banks)

using short8 = __attribute__((ext_vector_type(8))) short;
using f32x4  = __attribute__((ext_vector_type(4))) float;

// ---------------------------------------------------------------- utilities

__device__ __forceinline__ float sigm(float x) { return 1.f / (1.f + expf(-x)); }

__device__ __forceinline__ f32x4 mfma16(short8 a, short8 b, f32x4 c) {
  return __builtin_amdgcn_mfma_f32_16x16x32_bf16(a, b, c, 0, 0, 0);
}

__device__ __forceinline__ void gld_lds16(const void* g, void* l) {
  __builtin_amdgcn_global_load_lds(
      (const __attribute__((address_space(1))) void*)g,
      (__attribute__((address_space(3))) void*)l, 16, 0, 0);
}

// RNE bf16 split: v ~= hi + lo
__device__ __forceinline__ void bf16split(float v, short& h, short& l) {
  unsigned u = __float_as_uint(v);
  unsigned hb = (u + 0x7fffu + ((u >> 16) & 1u)) & 0xffff0000u;
  float res = v - __uint_as_float(hb);
  unsigned u2 = __float_as_uint(res);
  h = (short)(hb >> 16);
  l = (short)((u2 + 0x7fffu + ((u2 >> 16) & 1u)) >> 16);
}

__device__ __forceinline__ short bf16hi(float v) {
  unsigned u = __float_as_uint(v);
  return (short)((u + 0x7fffu + ((u >> 16) & 1u)) >> 16);
}

// ---------------------------------------------------------------- Wc kernel
// Wc[c][k] = dot(w_ih[c,:], conv_w[k,:]); conv_w transposed into LDS so the
// inner loop is broadcast w_ih read + stride-1 LDS read. 12 blocks x 25 rows.
__global__ __launch_bounds__(256) void k_wc(const float* __restrict__ w_ih,
                                            const float* __restrict__ conv_w,
                                            float* __restrict__ Wc) {
  __shared__ float cwT[100 * 100];  // cwT[t*100+k] = conv_w[k*100+t]
  const int tid = threadIdx.x;
  for (int idx = tid; idx < 10000; idx += 256) {
    int k = idx / 100, t = idx - k * 100;
    cwT[t * 100 + k] = conv_w[idx];
  }
  __syncthreads();
  const int cBase = blockIdx.x * 25;   // 12 blocks x 25 c-rows (c < 300)
  for (int o = tid; o < 25 * 100; o += 256) {
    int c = cBase + o / 100;
    int k = o - (o / 100) * 100;
    const float* wr = w_ih + (size_t)c * 100;
    float acc = 0.f;
    for (int t = 0; t < 100; ++t) acc = fmaf(wr[t], cwT[t * 100 + k], acc);
    Wc[(size_t)c * 100 + k] = acc;
  }
}

// ---------------------------------------------------------------- combined pack + gather
__global__ void k_packAll(const int* __restrict__ x, const float* __restrict__ emb,
                          const int* __restrict__ batch, const float* __restrict__ Wc,
                          const float* __restrict__ w_hh, const float* __restrict__ w2,
                          const float* __restrict__ w3,
                          short8* __restrict__ Bhi, short8* __restrict__ Blo,
                          short8* __restrict__ Whi,
                          float4* __restrict__ h0, int* __restrict__ last_idx,
                          int NNODE, int NT, int N) {
  int gid = blockIdx.x * 256 + threadIdx.x;
  const int embN = NT * 4 * 64;
  const int wN = 8 * 7 * 4 * 64;
  if (gid < embN) {
    int lane = gid & 63;
    int kt = (gid >> 6) & 3;
    int rt = gid >> 8;
    int r = rt * 16 + (lane & 15);
    if (r >= NNODE) r = NNODE - 1;
    int k0 = kt * 32 + (lane >> 4) * 8;
    float4 f0 = make_float4(0.f, 0.f, 0.f, 0.f);
    float4 f1 = make_float4(0.f, 0.f, 0.f, 0.f);
    if (k0 < 100)     f0 = *(const float4*)(emb + (size_t)r * DDIM + k0);
    if (k0 + 4 < 100) f1 = *(const float4*)(emb + (size_t)r * DDIM + k0 + 4);
    float v[8] = {f0.x, f0.y, f0.z, f0.w, f1.x, f1.y, f1.z, f1.w};
    short8 h, l;
#pragma unroll
    for (int j = 0; j < 8; ++j) {
      short hh, ll;
      bf16split(v[j], hh, ll);
      h[j] = hh; l[j] = ll;
    }
    Bhi[gid] = h;
    Blo[gid] = l;
  } else if (gid < embN + wN) {
    int wg = gid - embN;
    int lane = wg & 63;
    int kt = (wg >> 6) & 3;
    int snt = wg >> 8;
    int nt = snt % 7;
    int s = snt / 7;
    int d = nt * 16 + (lane & 15);
    int k0 = kt * 32 + (lane >> 4) * 8;
    short8 h;
#pragma unroll
    for (int j = 0; j < 8; ++j) {
      int k = k0 + j;
      float v = 0.f;
      if (d < 100 && k < 100) {
        if (s < 3) {
          v = Wc[(size_t)(s * 100 + d) * 100 + k];
        } else if (s < 6) {
          v = w_hh[(size_t)((s - 3) * 100 + d) * 100 + k];
        } else if (s == 6) {
          v = w2[(size_t)d * 100 + k];
        } else {
          v = w3[(size_t)d * 100 + k];
        }
      }
      h[j] = bf16hi(v);
    }
    Whi[wg] = h;
  } else {
    int i = gid - embN - wN;
    if (i < N * 25) {
      int node = i / 25, c = i - node * 25;
      h0[i] = *(const float4*)(emb + (size_t)(x[node] - 1) * DDIM + 4 * c);
    }
    if (i < N) {
      if (i == N - 1 || batch[i + 1] != batch[i]) last_idx[batch[i]] = i;
    }
  }
}

// ---------------------------------------------------------------- aggregation
__global__ __launch_bounds__(512, 1) void k_aggregate(
    const int* __restrict__ ei, const float* __restrict__ h0,
    float* __restrict__ aggH, int E) {
  __shared__ float acc[256 * DDIM];  // 100 KB
  const int tid = threadIdx.x;
  const int lane = tid & 63;
  const int wave = tid >> 6;         // 0..7
  const int r0 = blockIdx.x * 256;

  for (int idx = tid; idx < 256 * DDIM / 4; idx += 512)
    ((float4*)acc)[idx] = make_float4(0.f, 0.f, 0.f, 0.f);
  __syncthreads();

  const int per = E >> 3;            // multiple of 256
  const int base = wave * per;
  for (int it = 0; it < per; it += 256) {
    int e0 = base + it + lane * 4;
    int4 d4 = *(const int4*)(ei + E + e0);
    int4 s4 = *(const int4*)(ei + e0);
    int darr[4] = {d4.x, d4.y, d4.z, d4.w};
    int sarr[4] = {s4.x, s4.y, s4.z, s4.w};
#pragma unroll
    for (int j = 0; j < 4; ++j) {
      int dj = darr[j] - r0;
      bool match = (unsigned)dj < 256u;
      unsigned long long mask = __ballot(match);
      while (mask) {
        int bit = __ffsll(mask) - 1;
        mask &= mask - 1;
        int ds = __shfl(dj, bit, 64);
        int ss = __shfl(sarr[j], bit, 64);
        if (lane < 25) {
          float4 v = *(const float4*)(h0 + (size_t)ss * DDIM + 4 * lane);
          float* a = acc + ds * DDIM + 4 * lane;
          atomicAdd(a + 0, v.x); atomicAdd(a + 1, v.y);
          atomicAdd(a + 2, v.z); atomicAdd(a + 3, v.w);
        }
      }
    }
  }
  __syncthreads();
  float4* of = (float4*)(aggH + (size_t)r0 * DDIM);
  for (int idx = tid; idx < 256 * DDIM / 4; idx += 512)
    of[idx] = ((const float4*)acc)[idx];
}

// ---------------------------------------------------------------- session pooling
__global__ __launch_bounds__(256) void k_session(
    const float* __restrict__ xh, const float* __restrict__ t2,
    const float* __restrict__ t3v,
    const float* __restrict__ q_w, const float* __restrict__ q_b,
    const int* __restrict__ last_idx, float* __restrict__ Scat, int B) {
  int sid = blockIdx.x * 4 + (threadIdx.x >> 6);
  if (sid >= B) return;
  const int lane = threadIdx.x & 63;
  const int g = lane >> 4;
  const int s = lane & 15;
  const int start = (sid == 0) ? 0 : last_idx[sid - 1] + 1;
  const int end = last_idx[sid];

  float vr[7], t3r[7], qr[7];
#pragma unroll
  for (int k = 0; k < 7; ++k) {
    int c = s + 16 * k;
    bool ok = c < DDIM;
    vr[k]  = ok ? xh[(size_t)end * DDIM + c] : 0.f;
    t3r[k] = ok ? t3v[(size_t)sid * DDIM + c] : 0.f;
    qr[k]  = ok ? q_w[c] : 0.f;
  }
  const float qb = q_b[0];

  float m = -INFINITY, den = 0.f;
  float ss[7] = {}, sg[7] = {};
  for (int i = start; i <= end; i += 4) {
    int ni = i + g;
    bool act = ni <= end;
    int nrow = act ? ni : end;
    float xv[7];
    float l = 0.f, ga = 0.f;
#pragma unroll
    for (int k = 0; k < 7; ++k) {
      int c = s + 16 * k;
      float x = (c < DDIM) ? xh[(size_t)nrow * DDIM + c] : 0.f;
      float tv = (c < DDIM) ? t2[(size_t)nrow * DDIM + c] : 0.f;
      xv[k] = x;
      l = fmaf(x, vr[k], l);
      ga = fmaf(qr[k], sigm(tv + t3r[k]), ga);
    }
#pragma unroll
    for (int o = 1; o <= 8; o <<= 1) {
      l += __shfl_xor(l, o, 64);
      ga += __shfl_xor(ga, o, 64);
    }
    float ls = act ? l : -INFINITY;
    float alpha = act ? (ga + qb) : 0.f;
    float mn = fmaxf(m, ls);
    float cf = (m == -INFINITY) ? 0.f : expf(m - mn);
    float p = act ? expf(ls - mn) : 0.f;
    den = den * cf + p;
#pragma unroll
    for (int k = 0; k < 7; ++k) {
      ss[k] = ss[k] * cf + p * xv[k];
      sg[k] = fmaf(alpha, xv[k], sg[k]);
    }
    m = mn;
  }
  float mAll = m;
  mAll = fmaxf(mAll, __shfl_xor(mAll, 16, 64));
  mAll = fmaxf(mAll, __shfl_xor(mAll, 32, 64));
  float sc = (m == -INFINITY) ? 0.f : expf(m - mAll);
  float dv = den * sc;
  dv += __shfl_xor(dv, 16, 64);
  dv += __shfl_xor(dv, 32, 64);
  float inv = 1.f / dv;
  float* Sc = Scat + (size_t)sid * 300;
#pragma unroll
  for (int k = 0; k < 7; ++k) {
    float sv = ss[k] * sc;
    float gv = sg[k];
    sv += __shfl_xor(sv, 16, 64);  sv += __shfl_xor(sv, 32, 64);
    gv += __shfl_xor(gv, 16, 64);  gv += __shfl_xor(gv, 32, 64);
    int c = s + 16 * k;
    if (g == 0 && c < DDIM) {
      Sc[c] = sv * inv;
      Sc[100 + c] = gv;
      Sc[200 + c] = vr[k];
    }
  }
}

// hi-only A fragment loads for one 16-row m-tile (K=100 padded to 128)
__device__ __forceinline__ void load_afragsH(const float* __restrict__ A, int rowBase,
                                             int lane, short8 ah[4]) {
  int r = rowBase + (lane & 15);
  int g = lane >> 4;
#pragma unroll
  for (int kt = 0; kt < 4; ++kt) {
    int k0 = kt * 32 + g * 8;
    float4 f0 = make_float4(0.f, 0.f, 0.f, 0.f);
    float4 f1 = make_float4(0.f, 0.f, 0.f, 0.f);
    if (k0 < 100)     f0 = *(const float4*)(A + (size_t)r * DDIM + k0);
    if (k0 + 4 < 100) f1 = *(const float4*)(A + (size_t)r * DDIM + k0 + 4);
    short8 h;
    h[0] = bf16hi(f0.x); h[1] = bf16hi(f0.y); h[2] = bf16hi(f0.z); h[3] = bf16hi(f0.w);
    h[4] = bf16hi(f1.x); h[5] = bf16hi(f1.y); h[6] = bf16hi(f1.z); h[7] = bf16hi(f1.w);
    ah[kt] = h;
  }
}

__device__ __forceinline__ void load_afragsHg(const float* __restrict__ A,
                                              const int* __restrict__ idx, int base,
                                              int lane, short8 ah[4]) {
  int r = idx[base + (lane & 15)];
  int g = lane >> 4;
#pragma unroll
  for (int kt = 0; kt < 4; ++kt) {
    int k0 = kt * 32 + g * 8;
    float4 f0 = make_float4(0.f, 0.f, 0.f, 0.f);
    float4 f1 = make_float4(0.f, 0.f, 0.f, 0.f);
    if (k0 < 100)     f0 = *(const float4*)(A + (size_t)r * DDIM + k0);
    if (k0 + 4 < 100) f1 = *(const float4*)(A + (size_t)r * DDIM + k0 + 4);
    short8 h;
    h[0] = bf16hi(f0.x); h[1] = bf16hi(f0.y); h[2] = bf16hi(f0.z); h[3] = bf16hi(f0.w);
    h[4] = bf16hi(f1.x); h[5] = bf16hi(f1.y); h[6] = bf16hi(f1.z); h[7] = bf16hi(f1.w);
    ah[kt] = h;
  }
}

// ---------------------------------------------------------------- fused GGC+GRU + t2
// Computes xh = relu(GRU(...)) into a per-wave LDS stripe, dumps it as 400B-
// contiguous float4 stores, re-reads MFMA A-frags from LDS (no global round
// trip), computes t2 = xh@w2^T + b2 into the same stripe, dumps t2 likewise.
__global__ __launch_bounds__(256) void k_grufused(
    const float* __restrict__ aggH, const float* __restrict__ h0,
    const short8* __restrict__ Whi,
    const float* __restrict__ b_ih, const float* __restrict__ b_hh,
    const float* __restrict__ b2,
    float* __restrict__ xh, float* __restrict__ t2) {
  __shared__ float X[4 * 32 * XS];   // 55.3 KB (per-wave [32][XS] stripe)
  const int lane = threadIdx.x & 63;
  const int wave = threadIdx.x >> 6;
  const int rowBase = blockIdx.x * 128 + wave * 32;
  float* xs = &X[wave * 32 * XS];
  short8 aI0[4], aI1[4], aH0[4], aH1[4];
  load_afragsH(aggH, rowBase, lane, aI0);
  load_afragsH(aggH, rowBase + 16, lane, aI1);
  load_afragsH(h0, rowBase, lane, aH0);
  load_afragsH(h0, rowBase + 16, lane, aH1);
  const int c0 = lane & 15;
  const int r0 = (lane >> 4) * 4;

  for (int nt = 0; nt < 7; ++nt) {
    int d = nt * 16 + c0;
    f32x4 a0[6] = {};
    f32x4 a1[6] = {};
#pragma unroll
    for (int s = 0; s < 6; ++s) {
#pragma unroll
      for (int kt = 0; kt < 4; ++kt) {
        short8 w = Whi[(((size_t)s * 7 + nt) * 4 + kt) * 64 + lane];
        if (s < 3) {
          a0[s] = mfma16(aI0[kt], w, a0[s]);
          a1[s] = mfma16(aI1[kt], w, a1[s]);
        } else {
          a0[s] = mfma16(aH0[kt], w, a0[s]);
          a1[s] = mfma16(aH1[kt], w, a1[s]);
        }
      }
    }
    if (d < 100) {
      float bir = b_ih[d], biz = b_ih[100 + d], bin_ = b_ih[200 + d];
      float bhr = b_hh[d], bhz = b_hh[100 + d], bhn = b_hh[200 + d];
#pragma unroll
      for (int ri = 0; ri < 4; ++ri) {
        {
          int row = rowBase + r0 + ri;
          float r = sigm(a0[0][ri] + bir + a0[3][ri] + bhr);
          float z = sigm(a0[1][ri] + biz + a0[4][ri] + bhz);
          float n = tanhf(a0[2][ri] + bin_ + r * (a0[5][ri] + bhn));
          float h0v = h0[(size_t)row * DDIM + d];
          float v = (1.f - z) * n + z * h0v;
          xs[(r0 + ri) * XS + d] = v > 0.f ? v : 0.f;
        }
        {
          int row = rowBase + 16 + r0 + ri;
          float r = sigm(a1[0][ri] + bir + a1[3][ri] + bhr);
          float z = sigm(a1[1][ri] + biz + a1[4][ri] + bhz);
          float n = tanhf(a1[2][ri] + bin_ + r * (a1[5][ri] + bhn));
          float h0v = h0[(size_t)row * DDIM + d];
          float v = (1.f - z) * n + z * h0v;
          xs[(16 + r0 + ri) * XS + d] = v > 0.f ? v : 0.f;
        }
      }
    }
  }

  // dump xh: lanes 0..49 cover 2 rows x 25 float4 per pass (wave-private LDS)
  const int lr = lane / 25;
  const int lc4 = (lane - lr * 25) * 4;
  if (lane < 50) {
#pragma unroll
    for (int p = 0; p < 16; ++p) {
      int row = p * 2 + lr;
      f32x4 v = *(const f32x4*)&xs[row * XS + lc4];
      *(f32x4*)(xh + (size_t)(rowBase + row) * DDIM + lc4) = v;
    }
  }

  // re-read xh as MFMA A-frags from LDS
  short8 xa0[4], xa1[4];
  {
    int r = lane & 15;
    int g = lane >> 4;
#pragma unroll
    for (int kt = 0; kt < 4; ++kt) {
      int k0 = kt * 32 + g * 8;
      short8 h0f, h1f;
#pragma unroll
      for (int j = 0; j < 8; ++j) {
        int k = k0 + j;
        float v0 = (k < 100) ? xs[r * XS + k] : 0.f;
        float v1 = (k < 100) ? xs[(16 + r) * XS + k] : 0.f;
        h0f[j] = bf16hi(v0);
        h1f[j] = bf16hi(v1);
      }
      xa0[kt] = h0f;
      xa1[kt] = h1f;
    }
  }

  // t2 = xh @ w2^T + b2 into the stripe, then dump
  for (int nt = 0; nt < 7; ++nt) {
    int d = nt * 16 + c0;
    f32x4 ac0 = {0.f, 0.f, 0.f, 0.f};
    f32x4 ac1 = {0.f, 0.f, 0.f, 0.f};
#pragma unroll
    for (int kt = 0; kt < 4; ++kt) {
      short8 w = Whi[(((size_t)6 * 7 + nt) * 4 + kt) * 64 + lane];
      ac0 = mfma16(xa0[kt], w, ac0);
      ac1 = mfma16(xa1[kt], w, ac1);
    }
    if (d < 100) {
      float b = b2[d];
#pragma unroll
      for (int ri = 0; ri < 4; ++ri) {
        xs[(r0 + ri) * XS + d] = ac0[ri] + b;
        xs[(16 + r0 + ri) * XS + d] = ac1[ri] + b;
      }
    }
  }
  if (lane < 50) {
#pragma unroll
    for (int p = 0; p < 16; ++p) {
      int row = p * 2 + lr;
      f32x4 v = *(const f32x4*)&xs[row * XS + lc4];
      *(f32x4*)(t2 + (size_t)(rowBase + row) * DDIM + lc4) = v;
    }
  }
}

// t3v = xh[lastI] @ w3^T + b3  (32 blocks)
__global__ __launch_bounds__(256) void k_t3v(
    const float* __restrict__ xh, const short8* __restrict__ Whi,
    const float* __restrict__ b3, const int* __restrict__ lastI,
    float* __restrict__ t3v) {
  const int lane = threadIdx.x & 63;
  const int wave = threadIdx.x >> 6;
  const int rowBase = blockIdx.x * 128 + wave * 32;
  short8 a0[4], a1[4];
  load_afragsHg(xh, lastI, rowBase, lane, a0);
  load_afragsHg(xh, lastI, rowBase + 16, lane, a1);
  const int c0 = lane & 15;
  const int r0 = (lane >> 4) * 4;

  for (int nt = 0; nt < 7; ++nt) {
    int d = nt * 16 + c0;
    f32x4 ac0 = {0.f, 0.f, 0.f, 0.f};
    f32x4 ac1 = {0.f, 0.f, 0.f, 0.f};
#pragma unroll
    for (int kt = 0; kt < 4; ++kt) {
      short8 w = Whi[(((size_t)7 * 7 + nt) * 4 + kt) * 64 + lane];
      ac0 = mfma16(a0[kt], w, ac0);
      ac1 = mfma16(a1[kt], w, ac1);
    }
    if (d < 100) {
      float b = b3[d];
#pragma unroll
      for (int ri = 0; ri < 4; ++ri) {
        t3v[(size_t)(rowBase + r0 + ri) * DDIM + d] = ac0[ri] + b;
        t3v[(size_t)(rowBase + 16 + r0 + ri) * DDIM + d] = ac1[ri] + b;
      }
    }
  }
}

// ---------------------------------------------------------------- S GEMM -> packed frags
__global__ __launch_bounds__(256, 2) void k_gemmS(
    const float* __restrict__ A, const float* __restrict__ Bm,
    const float* __restrict__ bias, short* __restrict__ Ph, short* __restrict__ Pl,
    int M) {
  __shared__ float4 As4[25 * 128];
  __shared__ float4 Bs4[25 * 64];
  const int m0 = blockIdx.y * 128;
  const int n0 = blockIdx.x * 64;
  const int t = threadIdx.x;
  const int tx = t & 15;
  const int ty = t >> 4;
  float acc[8][4] = {};

  for (int kt = 0; kt < 300; kt += 100) {
    for (int idx = t; idx < 128 * 25; idx += 256) {
      int r = idx / 25, k4 = idx - r * 25;
      int ar = m0 + r; if (ar >= M) ar = M - 1;
      float4 v = *(const float4*)(A + (size_t)ar * 300 + kt + 4 * k4);
      As4[k4 * 128 + (r ^ (k4 & 7))] = v;
    }
    for (int idx = t; idx < 64 * 25; idx += 256) {
      int r = idx / 25, k4 = idx - r * 25;
      int br = n0 + r;
      float4 v = make_float4(0.f, 0.f, 0.f, 0.f);
      if (br < 100) v = *(const float4*)(Bm + (size_t)br * 300 + kt + 4 * k4);
      Bs4[k4 * 64 + (r ^ (k4 & 7))] = v;
    }
    __syncthreads();
#pragma unroll 5
    for (int k4 = 0; k4 < 25; ++k4) {
      const int s = k4 & 7;
      float4 av[8], bv[4];
#pragma unroll
      for (int i = 0; i < 8; ++i) av[i] = As4[k4 * 128 + ((ty + 16 * i) ^ s)];
#pragma unroll
      for (int j = 0; j < 4; ++j) bv[j] = Bs4[k4 * 64 + ((tx + 16 * j) ^ s)];
#pragma unroll
      for (int i = 0; i < 8; ++i) {
#pragma unroll
        for (int j = 0; j < 4; ++j) {
          acc[i][j] = fmaf(av[i].x, bv[j].x, acc[i][j]);
          acc[i][j] = fmaf(av[i].y, bv[j].y, acc[i][j]);
          acc[i][j] = fmaf(av[i].z, bv[j].z, acc[i][j]);
          acc[i][j] = fmaf(av[i].w, bv[j].w, acc[i][j]);
        }
      }
    }
    __syncthreads();
  }

#pragma unroll
  for (int i = 0; i < 8; ++i) {
    int row = m0 + ty + 16 * i;
    if (row >= M) continue;
#pragma unroll
    for (int j = 0; j < 4; ++j) {
      int col = n0 + tx + 16 * j;   // 0..127 (>=100 -> zero pad slot)
      float v = (col < 100) ? (acc[i][j] + bias[col]) : 0.f;
      short hh, ll;
      bf16split(v, hh, ll);
      int rt = row >> 4, kt = col >> 5;
      int lane_t = (row & 15) + 16 * ((col >> 3) & 3);
      size_t base = ((((size_t)rt * 4 + kt) * 64 + lane_t) << 3) + (col & 7);
      Ph[base] = hh;
      Pl[base] = ll;
    }
  }
}

// ---------------------------------------------------------------- big MFMA GEMM (r7-verbatim)
__global__ __launch_bounds__(256) void k_bigmm(
    const short8* __restrict__ Ahi, const short8* __restrict__ Alo,
    const short8* __restrict__ Bhi, const short8* __restrict__ Blo,
    float* __restrict__ out, int NT, int NTCHUNK, int NCOLS) {
  __shared__ short8 Bs[PFD * 8 * 64];   // 32 KB ring
  __shared__ float Xp[4 * 32 * 64];     // 32 KB transpose stripes (8KB/wave)
  const int lane = threadIdx.x & 63;
  const int wave = threadIdx.x >> 6;
  const int mt0 = blockIdx.x * 8 + wave * 2;

  short8 ah[2][4], al[2][4];
#pragma unroll
  for (int mi = 0; mi < 2; ++mi)
#pragma unroll
    for (int kt = 0; kt < 4; ++kt) {
      size_t off = ((size_t)(mt0 + mi) * 4 + kt) * 64 + lane;
      ah[mi][kt] = Ahi[off];
      al[mi][kt] = Alo[off];
    }

  const int nt0 = blockIdx.y * NTCHUNK;
  const int nt1 = min(NT, nt0 + NTCHUNK);
  const int r0 = (lane >> 4) * 4;
  const int c0 = lane & 15;
  float* xp = &Xp[wave * 32 * 64];

  auto issueB = [&](int nt) {
    int s = nt & (PFD - 1);
    gld_lds16(Bhi + ((size_t)nt * 4 + wave) * 64 + lane, &Bs[(s * 8 + wave) * 64]);
    gld_lds16(Blo + ((size_t)nt * 4 + wave) * 64 + lane, &Bs[(s * 8 + 4 + wave) * 64]);
  };

  for (int i = 0; i < PFD && nt0 + i < nt1; ++i) issueB(nt0 + i);
  asm volatile("s_waitcnt vmcnt(6)" ::: "memory");
  __builtin_amdgcn_s_barrier();

  for (int g = nt0; g < nt1; g += NTG) {
    const int jn = min(NTG, nt1 - g);
    f32x4 acc[2][NTG] = {};
#pragma unroll
    for (int j = 0; j < NTG; ++j) {
      if (j >= jn) break;
      const int nt = g + j;
      const int s = nt & (PFD - 1);
      short8 bh[4], bl[4];
#pragma unroll
      for (int kt = 0; kt < 4; ++kt) {
        bh[kt] = Bs[(s * 8 + kt) * 64 + lane];
        bl[kt] = Bs[(s * 8 + 4 + kt) * 64 + lane];
      }
      asm volatile("s_waitcnt lgkmcnt(0)" ::: "memory");
      __builtin_amdgcn_s_barrier();
      if (nt + PFD < nt1) issueB(nt + PFD);
      __builtin_amdgcn_sched_barrier(0);
#pragma unroll
      for (int kt = 0; kt < 4; ++kt) {
        acc[0][j] = mfma16(ah[0][kt], bh[kt], acc[0][j]);
        acc[1][j] = mfma16(ah[1][kt], bh[kt], acc[1][j]);
        acc[0][j] = mfma16(ah[0][kt], bl[kt], acc[0][j]);
        acc[1][j] = mfma16(ah[1][kt], bl[kt], acc[1][j]);
        acc[0][j] = mfma16(al[0][kt], bh[kt], acc[0][j]);
        acc[1][j] = mfma16(al[1][kt], bh[kt], acc[1][j]);
      }
      asm volatile("s_waitcnt vmcnt(14)" ::: "memory");
      __builtin_amdgcn_s_barrier();
    }
#pragma unroll
    for (int mi = 0; mi < 2; ++mi)
#pragma unroll
      for (int j = 0; j < NTG; ++j) {
        if (j < jn) {
#pragma unroll
          for (int r = 0; r < 4; ++r) {
            int rl = mi * 16 + r0 + r;
            int cl = j * 16 + c0;
            xp[rl * 64 + (cl ^ (((rl >> 2) & 3) << 4))] = acc[mi][j][r];
          }
        }
      }
    const int colbase = g * 16;
#pragma unroll
    for (int it = 0; it < 8; ++it) {
      int rl = it * 4 + (lane >> 4);
      int cl = 4 * c0;
      if (cl < jn * 16) {
        f32x4 v = *(const f32x4*)&xp[rl * 64 + (cl ^ (((rl >> 2) & 3) << 4))];
        int row = mt0 * 16 + rl;
        __builtin_nontemporal_store(v, (f32x4*)(out + (size_t)row * NCOLS + colbase + cl));
      }
    }
  }
}

// ---------------------------------------------------------------- launcher

extern "C" void kernel_launch(void* const* d_in, const int* in_sizes, int n_in,
                              void* d_out, int out_size, void* d_ws, size_t ws_size,
                              hipStream_t stream) {
  const int*   x      = (const int*)d_in[0];
  const int*   ei     = (const int*)d_in[1];
  const int*   batch  = (const int*)d_in[2];
  const float* emb    = (const float*)d_in[4];
  const float* conv_w = (const float*)d_in[5];
  const float* w_ih   = (const float*)d_in[6];
  const float* w_hh   = (const float*)d_in[7];
  const float* b_ih   = (const float*)d_in[8];
  const float* b_hh   = (const float*)d_in[9];
  const float* q_w    = (const float*)d_in[10];
  const float* q_b    = (const float*)d_in[11];
  const float* w2     = (const float*)d_in[12];
  const float* b2     = (const float*)d_in[13];
  const float* w3     = (const float*)d_in[14];
  const float* b3     = (const float*)d_in[15];
  const float* w4     = (const float*)d_in[16];
  const float* b4     = (const float*)d_in[17];

  const int N = in_sizes[0];            // 49152
  const int E = in_sizes[1] / 2;        // 98304
  const int NNODE = in_sizes[4] / DDIM; // 50000
  const int B = out_size / NNODE;       // 4096

  size_t ND = (size_t)N * DDIM;
  float* ws   = (float*)d_ws;
  float* h0   = ws;            // [N,100]
  float* aggH = ws + ND;       // [N,100]
  float* xh   = ws + 2 * ND;   // [N,100]
  float* t2   = ws + 3 * ND;   // [N,100]
  float* aux  = ws + 4 * ND;
  float* t3v  = aux;                           // [B,100]
  float* Scat = t3v + (size_t)B * DDIM;        // [B,300]
  int*   lastI = (int*)(Scat + 3 * (size_t)B * DDIM); // [B]

  const int MT = (B + 15) / 16;          // 256
  const int NT = (NNODE + 15) / 16;      // 3125
  short8* Whi = (short8*)(lastI + B);    // 8 sets x [7][4][64]
  short8* Ahi = Whi + 8 * 7 * 4 * 64;
  short8* Alo = Ahi + (size_t)MT * 4 * 64;
  short8* Bhi = Alo + (size_t)MT * 4 * 64;
  short8* Blo = Bhi + (size_t)NT * 4 * 64;
  float*  Wc  = (float*)(Blo + (size_t)NT * 4 * 64);  // [300,100]

  dim3 blk(256);
  const int nblkA = N / 128;   // 384
  const int nblkB = B / 128;   // 32

  int packTotal = NT * 4 * 64 + 8 * 7 * 4 * 64 + N * 25;
  k_wc<<<12, blk, 0, stream>>>(w_ih, conv_w, Wc);
  k_packAll<<<(packTotal + 255) / 256, blk, 0, stream>>>(
      x, emb, batch, Wc, w_hh, w2, w3, Bhi, Blo, Whi,
      (float4*)h0, lastI, NNODE, NT, N);
  k_aggregate<<<N / 256, dim3(512), 0, stream>>>(ei, h0, aggH, E);
  k_grufused<<<nblkA, blk, 0, stream>>>(aggH, h0, Whi, b_ih, b_hh, b2, xh, t2);
  k_t3v<<<nblkB, blk, 0, stream>>>(xh, Whi, b3, lastI, t3v);
  k_session<<<(B + 3) / 4, blk, 0, stream>>>(xh, t2, t3v, q_w, q_b, lastI, Scat, B);
  k_gemmS<<<dim3(2, B / 128), blk, 0, stream>>>(Scat, w4, b4, (short*)Ahi, (short*)Alo, B);

  const int NTCHUNK = 48;                            // multiple of NTG
  const int NCHUNKS = (NT + NTCHUNK - 1) / NTCHUNK;  // 66
  k_bigmm<<<dim3(nblkB, NCHUNKS), blk, 0, stream>>>(
      Ahi, Alo, Bhi, Blo, (float*)d_out, NT, NTCHUNK, NNODE);
}

// Round 18
// 394.206 us; speedup vs baseline: 1.7876x; 1.0256x over previous
//
#include <hip/hip_runtime.h>
#include <math.h>

#define DDIM 100   // embed dim
#define PFD  4     // k_bigmm LDS ring depth
#define NTG  4     // k_bigmm n-tiles per store group

using short8 = __attribute__((ext_vector_type(8))) short;
using f32x4  = __attribute__((ext_vector_type(4))) float;

// ---------------------------------------------------------------- utilities

__device__ __forceinline__ float sigm(float x) { return 1.f / (1.f + expf(-x)); }

__device__ __forceinline__ f32x4 mfma16(short8 a, short8 b, f32x4 c) {
  return __builtin_amdgcn_mfma_f32_16x16x32_bf16(a, b, c, 0, 0, 0);
}

__device__ __forceinline__ void gld_lds16(const void* g, void* l) {
  __builtin_amdgcn_global_load_lds(
      (const __attribute__((address_space(1))) void*)g,
      (__attribute__((address_space(3))) void*)l, 16, 0, 0);
}

// RNE bf16 split: v ~= hi + lo
__device__ __forceinline__ void bf16split(float v, short& h, short& l) {
  unsigned u = __float_as_uint(v);
  unsigned hb = (u + 0x7fffu + ((u >> 16) & 1u)) & 0xffff0000u;
  float res = v - __uint_as_float(hb);
  unsigned u2 = __float_as_uint(res);
  h = (short)(hb >> 16);
  l = (short)((u2 + 0x7fffu + ((u2 >> 16) & 1u)) >> 16);
}

__device__ __forceinline__ short bf16hi(float v) {
  unsigned u = __float_as_uint(v);
  return (short)((u + 0x7fffu + ((u >> 16) & 1u)) >> 16);
}

// ---------------------------------------------------------------- Wc kernel
__global__ __launch_bounds__(256) void k_wc(const float* __restrict__ w_ih,
                                            const float* __restrict__ conv_w,
                                            float* __restrict__ Wc) {
  __shared__ float cwT[100 * 100];
  const int tid = threadIdx.x;
  for (int idx = tid; idx < 10000; idx += 256) {
    int k = idx / 100, t = idx - k * 100;
    cwT[t * 100 + k] = conv_w[idx];
  }
  __syncthreads();
  const int cBase = blockIdx.x * 25;
  for (int o = tid; o < 25 * 100; o += 256) {
    int c = cBase + o / 100;
    int k = o - (o / 100) * 100;
    const float* wr = w_ih + (size_t)c * 100;
    float acc = 0.f;
    for (int t = 0; t < 100; ++t) acc = fmaf(wr[t], cwT[t * 100 + k], acc);
    Wc[(size_t)c * 100 + k] = acc;
  }
}

// ---------------------------------------------------------------- pack (no gather)
__global__ void k_packAll(const int* __restrict__ batch, const float* __restrict__ emb,
                          const float* __restrict__ Wc,
                          const float* __restrict__ w_hh, const float* __restrict__ w2,
                          const float* __restrict__ w3,
                          short8* __restrict__ Bhi, short8* __restrict__ Blo,
                          short8* __restrict__ Whi, int* __restrict__ last_idx,
                          int NNODE, int NT, int N) {
  int gid = blockIdx.x * 256 + threadIdx.x;
  const int embN = NT * 4 * 64;
  const int wN = 8 * 7 * 4 * 64;
  if (gid < embN) {
    int lane = gid & 63;
    int kt = (gid >> 6) & 3;
    int rt = gid >> 8;
    int r = rt * 16 + (lane & 15);
    if (r >= NNODE) r = NNODE - 1;
    int k0 = kt * 32 + (lane >> 4) * 8;
    float4 f0 = make_float4(0.f, 0.f, 0.f, 0.f);
    float4 f1 = make_float4(0.f, 0.f, 0.f, 0.f);
    if (k0 < 100)     f0 = *(const float4*)(emb + (size_t)r * DDIM + k0);
    if (k0 + 4 < 100) f1 = *(const float4*)(emb + (size_t)r * DDIM + k0 + 4);
    float v[8] = {f0.x, f0.y, f0.z, f0.w, f1.x, f1.y, f1.z, f1.w};
    short8 h, l;
#pragma unroll
    for (int j = 0; j < 8; ++j) {
      short hh, ll;
      bf16split(v[j], hh, ll);
      h[j] = hh; l[j] = ll;
    }
    Bhi[gid] = h;
    Blo[gid] = l;
  } else if (gid < embN + wN) {
    int wg = gid - embN;
    int lane = wg & 63;
    int kt = (wg >> 6) & 3;
    int snt = wg >> 8;
    int nt = snt % 7;
    int s = snt / 7;
    int d = nt * 16 + (lane & 15);
    int k0 = kt * 32 + (lane >> 4) * 8;
    short8 h;
#pragma unroll
    for (int j = 0; j < 8; ++j) {
      int k = k0 + j;
      float v = 0.f;
      if (d < 100 && k < 100) {
        if (s < 3)      v = Wc[(size_t)(s * 100 + d) * 100 + k];
        else if (s < 6) v = w_hh[(size_t)((s - 3) * 100 + d) * 100 + k];
        else if (s == 6) v = w2[(size_t)d * 100 + k];
        else             v = w3[(size_t)d * 100 + k];
      }
      h[j] = bf16hi(v);
    }
    Whi[wg] = h;
  } else {
    int i = gid - embN - wN;
    if (i < N) {
      if (i == N - 1 || batch[i + 1] != batch[i]) last_idx[batch[i]] = i;
    }
  }
}

// ---------------------------------------------------------------- fused aggregate + GRU + t2
// Phase 1: edge scan -> LDS accumulator acc[256][100] (block owns 256 dst rows).
// Phase 2: per-wave 32 rows: aggH frags read from LDS, h0 frags via emb[x-1]
// (h0 never materialized); GRU -> xh into acc -> 400B dumps; t2 likewise.
__global__ __launch_bounds__(512, 1) void k_aggGru(
    const int* __restrict__ ei, const int* __restrict__ x,
    const float* __restrict__ emb, const short8* __restrict__ Whi,
    const float* __restrict__ b_ih, const float* __restrict__ b_hh,
    const float* __restrict__ b2,
    float* __restrict__ xh, float* __restrict__ t2, int E) {
  __shared__ float acc[256 * DDIM];  // 100 KB
  const int tid = threadIdx.x;
  const int lane = tid & 63;
  const int wave = tid >> 6;         // 0..7
  const int r0blk = blockIdx.x * 256;

  for (int idx = tid; idx < 256 * DDIM / 4; idx += 512)
    ((float4*)acc)[idx] = make_float4(0.f, 0.f, 0.f, 0.f);
  __syncthreads();

  // phase 1: scan edges; aggH[dst] += emb[x[src]-1]
  const int per = E >> 3;            // multiple of 256
  const int base = wave * per;
  for (int it = 0; it < per; it += 256) {
    int e0 = base + it + lane * 4;
    int4 d4 = *(const int4*)(ei + E + e0);
    int4 s4 = *(const int4*)(ei + e0);
    int darr[4] = {d4.x, d4.y, d4.z, d4.w};
    int sarr[4] = {s4.x, s4.y, s4.z, s4.w};
#pragma unroll
    for (int j = 0; j < 4; ++j) {
      int dj = darr[j] - r0blk;
      bool match = (unsigned)dj < 256u;
      unsigned long long mask = __ballot(match);
      while (mask) {
        int bit = __ffsll(mask) - 1;
        mask &= mask - 1;
        int ds = __shfl(dj, bit, 64);
        int ss = __shfl(sarr[j], bit, 64);
        if (lane < 25) {
          int er = x[ss] - 1;
          float4 v = *(const float4*)(emb + (size_t)er * DDIM + 4 * lane);
          float* a = acc + ds * DDIM + 4 * lane;
          atomicAdd(a + 0, v.x); atomicAdd(a + 1, v.y);
          atomicAdd(a + 2, v.z); atomicAdd(a + 3, v.w);
        }
      }
    }
  }
  __syncthreads();

  // phase 2: wave owns rows [lr, lr+32) local / [rowBase, rowBase+32) global
  const int lr = wave * 32;
  const int rowBase = r0blk + lr;
  const int c0 = lane & 15;
  const int rq = (lane >> 4) * 4;

  // aggH frags from LDS
  short8 aI0[4], aI1[4];
  {
    int r = lane & 15;
    int g = lane >> 4;
#pragma unroll
    for (int kt = 0; kt < 4; ++kt) {
      int k0 = kt * 32 + g * 8;
      short8 h0f, h1f;
#pragma unroll
      for (int j = 0; j < 8; ++j) {
        int k = k0 + j;
        float v0 = (k < 100) ? acc[(lr + r) * DDIM + k] : 0.f;
        float v1 = (k < 100) ? acc[(lr + 16 + r) * DDIM + k] : 0.f;
        h0f[j] = bf16hi(v0);
        h1f[j] = bf16hi(v1);
      }
      aI0[kt] = h0f;
      aI1[kt] = h1f;
    }
  }
  // h0 frags via emb[x[row]-1]
  short8 aH0[4], aH1[4];
  {
    int r0g = x[rowBase + (lane & 15)] - 1;
    int r1g = x[rowBase + 16 + (lane & 15)] - 1;
    int g = lane >> 4;
#pragma unroll
    for (int kt = 0; kt < 4; ++kt) {
      int k0 = kt * 32 + g * 8;
      float4 a0f = make_float4(0.f, 0.f, 0.f, 0.f), a1f = a0f;
      float4 b0f = a0f, b1f = a0f;
      if (k0 < 100) {
        a0f = *(const float4*)(emb + (size_t)r0g * DDIM + k0);
        b0f = *(const float4*)(emb + (size_t)r1g * DDIM + k0);
      }
      if (k0 + 4 < 100) {
        a1f = *(const float4*)(emb + (size_t)r0g * DDIM + k0 + 4);
        b1f = *(const float4*)(emb + (size_t)r1g * DDIM + k0 + 4);
      }
      float v0[8] = {a0f.x, a0f.y, a0f.z, a0f.w, a1f.x, a1f.y, a1f.z, a1f.w};
      float v1[8] = {b0f.x, b0f.y, b0f.z, b0f.w, b1f.x, b1f.y, b1f.z, b1f.w};
      short8 h0f, h1f;
#pragma unroll
      for (int j = 0; j < 8; ++j) {
        h0f[j] = bf16hi(v0[j]);
        h1f[j] = bf16hi(v1[j]);
      }
      aH0[kt] = h0f;
      aH1[kt] = h1f;
    }
  }
  // per-lane h0 row ids for the elementwise stage
  int xr0[4], xr1[4];
#pragma unroll
  for (int ri = 0; ri < 4; ++ri) {
    xr0[ri] = x[rowBase + rq + ri] - 1;
    xr1[ri] = x[rowBase + 16 + rq + ri] - 1;
  }

  for (int nt = 0; nt < 7; ++nt) {
    int d = nt * 16 + c0;
    f32x4 a0[6] = {};
    f32x4 a1[6] = {};
#pragma unroll
    for (int s = 0; s < 6; ++s) {
#pragma unroll
      for (int kt = 0; kt < 4; ++kt) {
        short8 w = Whi[(((size_t)s * 7 + nt) * 4 + kt) * 64 + lane];
        if (s < 3) {
          a0[s] = mfma16(aI0[kt], w, a0[s]);
          a1[s] = mfma16(aI1[kt], w, a1[s]);
        } else {
          a0[s] = mfma16(aH0[kt], w, a0[s]);
          a1[s] = mfma16(aH1[kt], w, a1[s]);
        }
      }
    }
    if (d < 100) {
      float bir = b_ih[d], biz = b_ih[100 + d], bin_ = b_ih[200 + d];
      float bhr = b_hh[d], bhz = b_hh[100 + d], bhn = b_hh[200 + d];
#pragma unroll
      for (int ri = 0; ri < 4; ++ri) {
        {
          float r = sigm(a0[0][ri] + bir + a0[3][ri] + bhr);
          float z = sigm(a0[1][ri] + biz + a0[4][ri] + bhz);
          float n = tanhf(a0[2][ri] + bin_ + r * (a0[5][ri] + bhn));
          float h0v = emb[(size_t)xr0[ri] * DDIM + d];
          float v = (1.f - z) * n + z * h0v;
          acc[(lr + rq + ri) * DDIM + d] = v > 0.f ? v : 0.f;
        }
        {
          float r = sigm(a1[0][ri] + bir + a1[3][ri] + bhr);
          float z = sigm(a1[1][ri] + biz + a1[4][ri] + bhz);
          float n = tanhf(a1[2][ri] + bin_ + r * (a1[5][ri] + bhn));
          float h0v = emb[(size_t)xr1[ri] * DDIM + d];
          float v = (1.f - z) * n + z * h0v;
          acc[(lr + 16 + rq + ri) * DDIM + d] = v > 0.f ? v : 0.f;
        }
      }
    }
  }

  // dump xh: lanes 0..49 cover 2 rows x 25 float4 per pass (wave-private)
  const int dr = lane / 25;
  const int dc4 = (lane - dr * 25) * 4;
  if (lane < 50) {
#pragma unroll
    for (int p = 0; p < 16; ++p) {
      int row = p * 2 + dr;
      f32x4 v = *(const f32x4*)&acc[(lr + row) * DDIM + dc4];
      *(f32x4*)(xh + (size_t)(rowBase + row) * DDIM + dc4) = v;
    }
  }

  // xh frags from LDS (no barrier: wave-private rows)
  short8 xa0[4], xa1[4];
  {
    int r = lane & 15;
    int g = lane >> 4;
#pragma unroll
    for (int kt = 0; kt < 4; ++kt) {
      int k0 = kt * 32 + g * 8;
      short8 h0f, h1f;
#pragma unroll
      for (int j = 0; j < 8; ++j) {
        int k = k0 + j;
        float v0 = (k < 100) ? acc[(lr + r) * DDIM + k] : 0.f;
        float v1 = (k < 100) ? acc[(lr + 16 + r) * DDIM + k] : 0.f;
        h0f[j] = bf16hi(v0);
        h1f[j] = bf16hi(v1);
      }
      xa0[kt] = h0f;
      xa1[kt] = h1f;
    }
  }

  // t2 = xh @ w2^T + b2 into acc, then dump
  for (int nt = 0; nt < 7; ++nt) {
    int d = nt * 16 + c0;
    f32x4 ac0 = {0.f, 0.f, 0.f, 0.f};
    f32x4 ac1 = {0.f, 0.f, 0.f, 0.f};
#pragma unroll
    for (int kt = 0; kt < 4; ++kt) {
      short8 w = Whi[(((size_t)6 * 7 + nt) * 4 + kt) * 64 + lane];
      ac0 = mfma16(xa0[kt], w, ac0);
      ac1 = mfma16(xa1[kt], w, ac1);
    }
    if (d < 100) {
      float b = b2[d];
#pragma unroll
      for (int ri = 0; ri < 4; ++ri) {
        acc[(lr + rq + ri) * DDIM + d] = ac0[ri] + b;
        acc[(lr + 16 + rq + ri) * DDIM + d] = ac1[ri] + b;
      }
    }
  }
  if (lane < 50) {
#pragma unroll
    for (int p = 0; p < 16; ++p) {
      int row = p * 2 + dr;
      f32x4 v = *(const f32x4*)&acc[(lr + row) * DDIM + dc4];
      *(f32x4*)(t2 + (size_t)(rowBase + row) * DDIM + dc4) = v;
    }
  }
}

// ---------------------------------------------------------------- session pooling
__global__ __launch_bounds__(256) void k_session(
    const float* __restrict__ xh, const float* __restrict__ t2,
    const float* __restrict__ t3v,
    const float* __restrict__ q_w, const float* __restrict__ q_b,
    const int* __restrict__ last_idx, float* __restrict__ Scat, int B) {
  int sid = blockIdx.x * 4 + (threadIdx.x >> 6);
  if (sid >= B) return;
  const int lane = threadIdx.x & 63;
  const int g = lane >> 4;
  const int s = lane & 15;
  const int start = (sid == 0) ? 0 : last_idx[sid - 1] + 1;
  const int end = last_idx[sid];

  float vr[7], t3r[7], qr[7];
#pragma unroll
  for (int k = 0; k < 7; ++k) {
    int c = s + 16 * k;
    bool ok = c < DDIM;
    vr[k]  = ok ? xh[(size_t)end * DDIM + c] : 0.f;
    t3r[k] = ok ? t3v[(size_t)sid * DDIM + c] : 0.f;
    qr[k]  = ok ? q_w[c] : 0.f;
  }
  const float qb = q_b[0];

  float m = -INFINITY, den = 0.f;
  float ss[7] = {}, sg[7] = {};
  for (int i = start; i <= end; i += 4) {
    int ni = i + g;
    bool act = ni <= end;
    int nrow = act ? ni : end;
    float xv[7];
    float l = 0.f, ga = 0.f;
#pragma unroll
    for (int k = 0; k < 7; ++k) {
      int c = s + 16 * k;
      float x = (c < DDIM) ? xh[(size_t)nrow * DDIM + c] : 0.f;
      float tv = (c < DDIM) ? t2[(size_t)nrow * DDIM + c] : 0.f;
      xv[k] = x;
      l = fmaf(x, vr[k], l);
      ga = fmaf(qr[k], sigm(tv + t3r[k]), ga);
    }
#pragma unroll
    for (int o = 1; o <= 8; o <<= 1) {
      l += __shfl_xor(l, o, 64);
      ga += __shfl_xor(ga, o, 64);
    }
    float ls = act ? l : -INFINITY;
    float alpha = act ? (ga + qb) : 0.f;
    float mn = fmaxf(m, ls);
    float cf = (m == -INFINITY) ? 0.f : expf(m - mn);
    float p = act ? expf(ls - mn) : 0.f;
    den = den * cf + p;
#pragma unroll
    for (int k = 0; k < 7; ++k) {
      ss[k] = ss[k] * cf + p * xv[k];
      sg[k] = fmaf(alpha, xv[k], sg[k]);
    }
    m = mn;
  }
  float mAll = m;
  mAll = fmaxf(mAll, __shfl_xor(mAll, 16, 64));
  mAll = fmaxf(mAll, __shfl_xor(mAll, 32, 64));
  float sc = (m == -INFINITY) ? 0.f : expf(m - mAll);
  float dv = den * sc;
  dv += __shfl_xor(dv, 16, 64);
  dv += __shfl_xor(dv, 32, 64);
  float inv = 1.f / dv;
  float* Sc = Scat + (size_t)sid * 300;
#pragma unroll
  for (int k = 0; k < 7; ++k) {
    float sv = ss[k] * sc;
    float gv = sg[k];
    sv += __shfl_xor(sv, 16, 64);  sv += __shfl_xor(sv, 32, 64);
    gv += __shfl_xor(gv, 16, 64);  gv += __shfl_xor(gv, 32, 64);
    int c = s + 16 * k;
    if (g == 0 && c < DDIM) {
      Sc[c] = sv * inv;
      Sc[100 + c] = gv;
      Sc[200 + c] = vr[k];
    }
  }
}

// hi-only A fragment loads (row-indexed gather)
__device__ __forceinline__ void load_afragsHg(const float* __restrict__ A,
                                              const int* __restrict__ idx, int base,
                                              int lane, short8 ah[4]) {
  int r = idx[base + (lane & 15)];
  int g = lane >> 4;
#pragma unroll
  for (int kt = 0; kt < 4; ++kt) {
    int k0 = kt * 32 + g * 8;
    float4 f0 = make_float4(0.f, 0.f, 0.f, 0.f);
    float4 f1 = make_float4(0.f, 0.f, 0.f, 0.f);
    if (k0 < 100)     f0 = *(const float4*)(A + (size_t)r * DDIM + k0);
    if (k0 + 4 < 100) f1 = *(const float4*)(A + (size_t)r * DDIM + k0 + 4);
    short8 h;
    h[0] = bf16hi(f0.x); h[1] = bf16hi(f0.y); h[2] = bf16hi(f0.z); h[3] = bf16hi(f0.w);
    h[4] = bf16hi(f1.x); h[5] = bf16hi(f1.y); h[6] = bf16hi(f1.z); h[7] = bf16hi(f1.w);
    ah[kt] = h;
  }
}

// t3v = xh[lastI] @ w3^T + b3  (32 blocks)
__global__ __launch_bounds__(256) void k_t3v(
    const float* __restrict__ xh, const short8* __restrict__ Whi,
    const float* __restrict__ b3, const int* __restrict__ lastI,
    float* __restrict__ t3v) {
  const int lane = threadIdx.x & 63;
  const int wave = threadIdx.x >> 6;
  const int rowBase = blockIdx.x * 128 + wave * 32;
  short8 a0[4], a1[4];
  load_afragsHg(xh, lastI, rowBase, lane, a0);
  load_afragsHg(xh, lastI, rowBase + 16, lane, a1);
  const int c0 = lane & 15;
  const int r0 = (lane >> 4) * 4;

  for (int nt = 0; nt < 7; ++nt) {
    int d = nt * 16 + c0;
    f32x4 ac0 = {0.f, 0.f, 0.f, 0.f};
    f32x4 ac1 = {0.f, 0.f, 0.f, 0.f};
#pragma unroll
    for (int kt = 0; kt < 4; ++kt) {
      short8 w = Whi[(((size_t)7 * 7 + nt) * 4 + kt) * 64 + lane];
      ac0 = mfma16(a0[kt], w, ac0);
      ac1 = mfma16(a1[kt], w, ac1);
    }
    if (d < 100) {
      float b = b3[d];
#pragma unroll
      for (int ri = 0; ri < 4; ++ri) {
        t3v[(size_t)(rowBase + r0 + ri) * DDIM + d] = ac0[ri] + b;
        t3v[(size_t)(rowBase + 16 + r0 + ri) * DDIM + d] = ac1[ri] + b;
      }
    }
  }
}

// ---------------------------------------------------------------- S GEMM -> packed frags
__global__ __launch_bounds__(256, 2) void k_gemmS(
    const float* __restrict__ A, const float* __restrict__ Bm,
    const float* __restrict__ bias, short* __restrict__ Ph, short* __restrict__ Pl,
    int M) {
  __shared__ float4 As4[25 * 128];
  __shared__ float4 Bs4[25 * 64];
  const int m0 = blockIdx.y * 128;
  const int n0 = blockIdx.x * 64;
  const int t = threadIdx.x;
  const int tx = t & 15;
  const int ty = t >> 4;
  float acc[8][4] = {};

  for (int kt = 0; kt < 300; kt += 100) {
    for (int idx = t; idx < 128 * 25; idx += 256) {
      int r = idx / 25, k4 = idx - r * 25;
      int ar = m0 + r; if (ar >= M) ar = M - 1;
      float4 v = *(const float4*)(A + (size_t)ar * 300 + kt + 4 * k4);
      As4[k4 * 128 + (r ^ (k4 & 7))] = v;
    }
    for (int idx = t; idx < 64 * 25; idx += 256) {
      int r = idx / 25, k4 = idx - r * 25;
      int br = n0 + r;
      float4 v = make_float4(0.f, 0.f, 0.f, 0.f);
      if (br < 100) v = *(const float4*)(Bm + (size_t)br * 300 + kt + 4 * k4);
      Bs4[k4 * 64 + (r ^ (k4 & 7))] = v;
    }
    __syncthreads();
#pragma unroll 5
    for (int k4 = 0; k4 < 25; ++k4) {
      const int s = k4 & 7;
      float4 av[8], bv[4];
#pragma unroll
      for (int i = 0; i < 8; ++i) av[i] = As4[k4 * 128 + ((ty + 16 * i) ^ s)];
#pragma unroll
      for (int j = 0; j < 4; ++j) bv[j] = Bs4[k4 * 64 + ((tx + 16 * j) ^ s)];
#pragma unroll
      for (int i = 0; i < 8; ++i) {
#pragma unroll
        for (int j = 0; j < 4; ++j) {
          acc[i][j] = fmaf(av[i].x, bv[j].x, acc[i][j]);
          acc[i][j] = fmaf(av[i].y, bv[j].y, acc[i][j]);
          acc[i][j] = fmaf(av[i].z, bv[j].z, acc[i][j]);
          acc[i][j] = fmaf(av[i].w, bv[j].w, acc[i][j]);
        }
      }
    }
    __syncthreads();
  }

#pragma unroll
  for (int i = 0; i < 8; ++i) {
    int row = m0 + ty + 16 * i;
    if (row >= M) continue;
#pragma unroll
    for (int j = 0; j < 4; ++j) {
      int col = n0 + tx + 16 * j;   // 0..127 (>=100 -> zero pad slot)
      float v = (col < 100) ? (acc[i][j] + bias[col]) : 0.f;
      short hh, ll;
      bf16split(v, hh, ll);
      int rt = row >> 4, kt = col >> 5;
      int lane_t = (row & 15) + 16 * ((col >> 3) & 3);
      size_t base = ((((size_t)rt * 4 + kt) * 64 + lane_t) << 3) + (col & 7);
      Ph[base] = hh;
      Pl[base] = ll;
    }
  }
}

// ---------------------------------------------------------------- big MFMA GEMM (r7-verbatim)
__global__ __launch_bounds__(256) void k_bigmm(
    const short8* __restrict__ Ahi, const short8* __restrict__ Alo,
    const short8* __restrict__ Bhi, const short8* __restrict__ Blo,
    float* __restrict__ out, int NT, int NTCHUNK, int NCOLS) {
  __shared__ short8 Bs[PFD * 8 * 64];   // 32 KB ring
  __shared__ float Xp[4 * 32 * 64];     // 32 KB transpose stripes (8KB/wave)
  const int lane = threadIdx.x & 63;
  const int wave = threadIdx.x >> 6;
  const int mt0 = blockIdx.x * 8 + wave * 2;

  short8 ah[2][4], al[2][4];
#pragma unroll
  for (int mi = 0; mi < 2; ++mi)
#pragma unroll
    for (int kt = 0; kt < 4; ++kt) {
      size_t off = ((size_t)(mt0 + mi) * 4 + kt) * 64 + lane;
      ah[mi][kt] = Ahi[off];
      al[mi][kt] = Alo[off];
    }

  const int nt0 = blockIdx.y * NTCHUNK;
  const int nt1 = min(NT, nt0 + NTCHUNK);
  const int r0 = (lane >> 4) * 4;
  const int c0 = lane & 15;
  float* xp = &Xp[wave * 32 * 64];

  auto issueB = [&](int nt) {
    int s = nt & (PFD - 1);
    gld_lds16(Bhi + ((size_t)nt * 4 + wave) * 64 + lane, &Bs[(s * 8 + wave) * 64]);
    gld_lds16(Blo + ((size_t)nt * 4 + wave) * 64 + lane, &Bs[(s * 8 + 4 + wave) * 64]);
  };

  for (int i = 0; i < PFD && nt0 + i < nt1; ++i) issueB(nt0 + i);
  asm volatile("s_waitcnt vmcnt(6)" ::: "memory");
  __builtin_amdgcn_s_barrier();

  for (int g = nt0; g < nt1; g += NTG) {
    const int jn = min(NTG, nt1 - g);
    f32x4 acc[2][NTG] = {};
#pragma unroll
    for (int j = 0; j < NTG; ++j) {
      if (j >= jn) break;
      const int nt = g + j;
      const int s = nt & (PFD - 1);
      short8 bh[4], bl[4];
#pragma unroll
      for (int kt = 0; kt < 4; ++kt) {
        bh[kt] = Bs[(s * 8 + kt) * 64 + lane];
        bl[kt] = Bs[(s * 8 + 4 + kt) * 64 + lane];
      }
      asm volatile("s_waitcnt lgkmcnt(0)" ::: "memory");
      __builtin_amdgcn_s_barrier();
      if (nt + PFD < nt1) issueB(nt + PFD);
      __builtin_amdgcn_sched_barrier(0);
#pragma unroll
      for (int kt = 0; kt < 4; ++kt) {
        acc[0][j] = mfma16(ah[0][kt], bh[kt], acc[0][j]);
        acc[1][j] = mfma16(ah[1][kt], bh[kt], acc[1][j]);
        acc[0][j] = mfma16(ah[0][kt], bl[kt], acc[0][j]);
        acc[1][j] = mfma16(ah[1][kt], bl[kt], acc[1][j]);
        acc[0][j] = mfma16(al[0][kt], bh[kt], acc[0][j]);
        acc[1][j] = mfma16(al[1][kt], bh[kt], acc[1][j]);
      }
      asm volatile("s_waitcnt vmcnt(14)" ::: "memory");
      __builtin_amdgcn_s_barrier();
    }
#pragma unroll
    for (int mi = 0; mi < 2; ++mi)
#pragma unroll
      for (int j = 0; j < NTG; ++j) {
        if (j < jn) {
#pragma unroll
          for (int r = 0; r < 4; ++r) {
            int rl = mi * 16 + r0 + r;
            int cl = j * 16 + c0;
            xp[rl * 64 + (cl ^ (((rl >> 2) & 3) << 4))] = acc[mi][j][r];
          }
        }
      }
    const int colbase = g * 16;
#pragma unroll
    for (int it = 0; it < 8; ++it) {
      int rl = it * 4 + (lane >> 4);
      int cl = 4 * c0;
      if (cl < jn * 16) {
        f32x4 v = *(const f32x4*)&xp[rl * 64 + (cl ^ (((rl >> 2) & 3) << 4))];
        int row = mt0 * 16 + rl;
        __builtin_nontemporal_store(v, (f32x4*)(out + (size_t)row * NCOLS + colbase + cl));
      }
    }
  }
}

// ---------------------------------------------------------------- launcher

extern "C" void kernel_launch(void* const* d_in, const int* in_sizes, int n_in,
                              void* d_out, int out_size, void* d_ws, size_t ws_size,
                              hipStream_t stream) {
  const int*   x      = (const int*)d_in[0];
  const int*   ei     = (const int*)d_in[1];
  const int*   batch  = (const int*)d_in[2];
  const float* emb    = (const float*)d_in[4];
  const float* conv_w = (const float*)d_in[5];
  const float* w_ih   = (const float*)d_in[6];
  const float* w_hh   = (const float*)d_in[7];
  const float* b_ih   = (const float*)d_in[8];
  const float* b_hh   = (const float*)d_in[9];
  const float* q_w    = (const float*)d_in[10];
  const float* q_b    = (const float*)d_in[11];
  const float* w2     = (const float*)d_in[12];
  const float* b2     = (const float*)d_in[13];
  const float* w3     = (const float*)d_in[14];
  const float* b3     = (const float*)d_in[15];
  const float* w4     = (const float*)d_in[16];
  const float* b4     = (const float*)d_in[17];

  const int N = in_sizes[0];            // 49152
  const int E = in_sizes[1] / 2;        // 98304
  const int NNODE = in_sizes[4] / DDIM; // 50000
  const int B = out_size / NNODE;       // 4096

  size_t ND = (size_t)N * DDIM;
  float* ws   = (float*)d_ws;
  float* xh   = ws;            // [N,100]
  float* t2   = ws + ND;       // [N,100]
  float* aux  = ws + 2 * ND;
  float* t3v  = aux;                           // [B,100]
  float* Scat = t3v + (size_t)B * DDIM;        // [B,300]
  int*   lastI = (int*)(Scat + 3 * (size_t)B * DDIM); // [B]

  const int MT = (B + 15) / 16;          // 256
  const int NT = (NNODE + 15) / 16;      // 3125
  short8* Whi = (short8*)(lastI + B);    // 8 sets x [7][4][64]
  short8* Ahi = Whi + 8 * 7 * 4 * 64;
  short8* Alo = Ahi + (size_t)MT * 4 * 64;
  short8* Bhi = Alo + (size_t)MT * 4 * 64;
  short8* Blo = Bhi + (size_t)NT * 4 * 64;
  float*  Wc  = (float*)(Blo + (size_t)NT * 4 * 64);  // [300,100]

  dim3 blk(256);
  const int nblkB = B / 128;   // 32

  int packTotal = NT * 4 * 64 + 8 * 7 * 4 * 64 + N;
  k_wc<<<12, blk, 0, stream>>>(w_ih, conv_w, Wc);
  k_packAll<<<(packTotal + 255) / 256, blk, 0, stream>>>(
      batch, emb, Wc, w_hh, w2, w3, Bhi, Blo, Whi, lastI, NNODE, NT, N);
  k_aggGru<<<N / 256, dim3(512), 0, stream>>>(ei, x, emb, Whi, b_ih, b_hh, b2,
                                              xh, t2, E);
  k_t3v<<<nblkB, blk, 0, stream>>>(xh, Whi, b3, lastI, t3v);
  k_session<<<(B + 3) / 4, blk, 0, stream>>>(xh, t2, t3v, q_w, q_b, lastI, Scat, B);
  k_gemmS<<<dim3(2, B / 128), blk, 0, stream>>>(Scat, w4, b4, (short*)Ahi, (short*)Alo, B);

  const int NTCHUNK = 48;                            // multiple of NTG
  const int NCHUNKS = (NT + NTCHUNK - 1) / NTCHUNK;  // 66
  k_bigmm<<<dim3(nblkB, NCHUNKS), blk, 0, stream>>>(
      Ahi, Alo, Bhi, Blo, (float*)d_out, NT, NTCHUNK, NNODE);
}